// Round 6
// baseline (319.110 us; speedup 1.0000x reference)
//
#include <hip/hip_runtime.h>

#define N_NODES 100000
#define C_DIM 128
#define E_EDGES 800000
#define V_OUT 50000
#define EN (E_EDGES + N_NODES)      /* 900000  per-layer CSR entries */
#define M2 (2 * N_NODES)
#define EN2 (2 * EN)                /* 1800000 */

#define BSHIFT 9                    /* 512 nodes per coarse bucket */
#define NBUCK_L ((N_NODES + 511) >> 9)   /* 196 per layer */
#define NBUCK2 (2 * NBUCK_L)             /* 392 */
#define CAP 8192                    /* slab capacity; avg fill ~4608 */
#define P1_CHUNK 4096
#define P1_PER_T (P1_CHUNK / 256)   /* 16 */
#define NCHUNK ((EN2 + P1_CHUNK - 1) / P1_CHUNK) /* 440 */

typedef unsigned int uint;
typedef unsigned short ushort;
typedef __attribute__((ext_vector_type(8))) short bf16x8;
typedef __attribute__((ext_vector_type(4))) float f32x4;

static __device__ __forceinline__ ushort f2bf(float f) {
    uint u = __float_as_uint(f);
    u += 0x7fffu + ((u >> 16) & 1);   // round-to-nearest-even
    return (ushort)(u >> 16);
}

// ---------------------------------------------------------------------------
// fp32 -> bf16 bulk convert (weights only)
// ---------------------------------------------------------------------------
__global__ void f2bf_kernel(const float* __restrict__ in, ushort* __restrict__ out, int n4)
{
    int i = blockIdx.x * 256 + threadIdx.x;
    if (i >= n4) return;
    float4 v = reinterpret_cast<const float4*>(in)[i];
    ushort4 r;
    r.x = f2bf(v.x); r.y = f2bf(v.y); r.z = f2bf(v.z); r.w = f2bf(v.w);
    reinterpret_cast<ushort4*>(out)[i] = r;
}

// mark nodes that appear in idx_mapping (races benign: all write 1)
__global__ void vflag_kernel(const int* __restrict__ idx, int* __restrict__ vflag)
{
    int v = blockIdx.x * 256 + threadIdx.x;
    if (v < V_OUT) vflag[idx[v]] = 1;
}

// ---------------------------------------------------------------------------
// MFMA GEMM: h[n,c] = sum_k x[n,k] * W[c,k] (bf16/fp32 in, fp32 acc, bf16 out)
// + fused scores a_s = h.att_src, a_d = h.att_dst.
// A frag: A[m=lane&15][k=quad*8+j]; B mirrored; D: col=lane&15, row=quad*4+r.
// ---------------------------------------------------------------------------
template <int IN_F32>
__global__ __launch_bounds__(256) void gemm_mfma(
    const void* __restrict__ xin, const ushort* __restrict__ Wb,
    const float* __restrict__ att_s, const float* __restrict__ att_d,
    ushort* __restrict__ hb, float* __restrict__ a_s, float* __restrict__ a_d)
{
    const int lane = threadIdx.x & 63;
    const int wv   = threadIdx.x >> 6;
    const int nb   = (blockIdx.x * 4 + wv) * 16;
    if (nb >= N_NODES) return;
    const int m    = lane & 15;
    const int quad = lane >> 4;

    bf16x8 a[4];
    if (IN_F32) {
        const float* xrow = (const float*)xin + (long)(nb + m) * 128 + quad * 8;
        #pragma unroll
        for (int ki = 0; ki < 4; ++ki) {
            float4 u = *reinterpret_cast<const float4*>(xrow + ki * 32);
            float4 v = *reinterpret_cast<const float4*>(xrow + ki * 32 + 4);
            bf16x8 t;
            t[0] = (short)f2bf(u.x); t[1] = (short)f2bf(u.y);
            t[2] = (short)f2bf(u.z); t[3] = (short)f2bf(u.w);
            t[4] = (short)f2bf(v.x); t[5] = (short)f2bf(v.y);
            t[6] = (short)f2bf(v.z); t[7] = (short)f2bf(v.w);
            a[ki] = t;
        }
    } else {
        const ushort* xrow = (const ushort*)xin + (long)(nb + m) * 128 + quad * 8;
        #pragma unroll
        for (int ki = 0; ki < 4; ++ki)
            a[ki] = *reinterpret_cast<const bf16x8*>(xrow + ki * 32);
    }

    float ps[4] = {0, 0, 0, 0}, pd[4] = {0, 0, 0, 0};

    #pragma unroll
    for (int ct = 0; ct < 8; ++ct) {
        const int c = ct * 16 + m;
        const ushort* wrow = Wb + (long)c * 128 + quad * 8;
        f32x4 acc = {0.f, 0.f, 0.f, 0.f};
        #pragma unroll
        for (int ki = 0; ki < 4; ++ki) {
            bf16x8 b = *reinterpret_cast<const bf16x8*>(wrow + ki * 32);
            acc = __builtin_amdgcn_mfma_f32_16x16x32_bf16(a[ki], b, acc, 0, 0, 0);
        }
        const float asc = att_s[c], adc = att_d[c];
        #pragma unroll
        for (int r = 0; r < 4; ++r) {
            const int node = nb + quad * 4 + r;
            hb[(long)node * 128 + c] = f2bf(acc[r]);
            ps[r] = fmaf(acc[r], asc, ps[r]);
            pd[r] = fmaf(acc[r], adc, pd[r]);
        }
    }
    #pragma unroll
    for (int r = 0; r < 4; ++r) {
        float s = ps[r], d = pd[r];
        #pragma unroll
        for (int x = 1; x < 16; x <<= 1) { s += __shfl_xor(s, x); d += __shfl_xor(d, x); }
        if (m == 0) {
            const int node = nb + quad * 4 + r;
            a_s[node] = s; a_d[node] = d;
        }
    }
}

// ---------------------------------------------------------------------------
// CSR build, pass 1: partition edges into 392 coarse buckets of 512 dst.
// ---------------------------------------------------------------------------
__global__ __launch_bounds__(256) void partition_kernel(
    const int* __restrict__ e1, const int* __restrict__ e2,
    int* __restrict__ cursor, uint* __restrict__ slab)
{
    __shared__ int cnt[NBUCK2];
    __shared__ int basearr[NBUCK2];
    const int tid = threadIdx.x;
    for (int i = tid; i < NBUCK2; i += 256) cnt[i] = 0;
    __syncthreads();

    const int e0 = blockIdx.x * P1_CHUNK;
    uint ent[P1_PER_T];
    int  bkt[P1_PER_T];
    #pragma unroll
    for (int i = 0; i < P1_PER_T; ++i) {
        int e = e0 + i * 256 + tid;
        bkt[i] = -1;
        if (e < EN2) {
            int src, dst, lb;
            if (e < EN) {
                if (e < E_EDGES) { src = e1[e]; dst = e1[E_EDGES + e]; }
                else             { src = dst = e - E_EDGES; }
                lb = 0;
            } else {
                int f = e - EN;
                if (f < E_EDGES) { src = e2[f]; dst = e2[E_EDGES + f]; }
                else             { src = dst = f - E_EDGES; }
                lb = NBUCK_L;
            }
            bkt[i] = lb + (dst >> BSHIFT);
            ent[i] = (uint)src | ((uint)(dst & 511) << 17);
            atomicAdd(&cnt[bkt[i]], 1);
        }
    }
    __syncthreads();
    for (int b = tid; b < NBUCK2; b += 256) {
        int c = cnt[b];
        basearr[b] = (c > 0) ? atomicAdd(&cursor[b], c) : 0;
        cnt[b] = 0;                       // reuse as rank counter
    }
    __syncthreads();
    #pragma unroll
    for (int i = 0; i < P1_PER_T; ++i) {
        if (bkt[i] >= 0) {
            int r = basearr[bkt[i]] + atomicAdd(&cnt[bkt[i]], 1);
            if (r < CAP) slab[(long)bkt[i] * CAP + r] = ent[i];
        }
    }
}

// exclusive scan of the 392 bucket counts; single wave
__global__ void bucket_scan(const int* __restrict__ cursor, int* __restrict__ bbase)
{
    const int lane = threadIdx.x;     // 64 threads
    int v[7]; int s = 0;
    #pragma unroll
    for (int i = 0; i < 7; ++i) {
        int idx = lane * 7 + i;
        v[i] = (idx < NBUCK2) ? cursor[idx] : 0;
        s += v[i];
    }
    int incl = s;
    #pragma unroll
    for (int d = 1; d < 64; d <<= 1) {
        int t = __shfl_up(incl, d);
        if (lane >= d) incl += t;
    }
    int excl = incl - s;
    #pragma unroll
    for (int i = 0; i < 7; ++i) {
        int idx = lane * 7 + i;
        if (idx < NBUCK2) bbase[idx] = excl;
        excl += v[i];
    }
}

// ---------------------------------------------------------------------------
// CSR build, pass 2: one workgroup per bucket -> local CSR in LDS.
// esrc entries stay PACKED (src | dst_local<<17) so the weights pass can
// recover dst without a separate edst array.
// ---------------------------------------------------------------------------
__global__ __launch_bounds__(256) void local_csr(
    const uint* __restrict__ slab, const int* __restrict__ cursor,
    const int* __restrict__ bbase, int* __restrict__ offs, uint* __restrict__ esrc)
{
    __shared__ uint ent[CAP];         // 32 KB
    __shared__ int deg[512];
    __shared__ int excl[512];
    const int b = blockIdx.x;
    const int tid = threadIdx.x;
    const int cnt = min(cursor[b], CAP);
    const int base = bbase[b];
    const int layer = (b >= NBUCK_L);
    const int node0 = (b - layer * NBUCK_L) << BSHIFT;
    const int obase = layer * N_NODES;
    const int nodes_n = min(512, N_NODES - node0);

    for (int i = tid; i < 512; i += 256) deg[i] = 0;
    __syncthreads();
    for (int i = tid; i < cnt; i += 256) {
        uint v = slab[(long)b * CAP + i];
        ent[i] = v;
        atomicAdd(&deg[v >> 17], 1);
    }
    __syncthreads();
    if (tid < 64) {                   // wave-0 scan of deg[512], 8 per lane
        int v8[8]; int s = 0;
        #pragma unroll
        for (int i = 0; i < 8; ++i) { v8[i] = deg[tid * 8 + i]; s += v8[i]; }
        int incl = s;
        #pragma unroll
        for (int d = 1; d < 64; d <<= 1) {
            int t = __shfl_up(incl, d);
            if (tid >= d) incl += t;
        }
        int e = incl - s;
        #pragma unroll
        for (int i = 0; i < 8; ++i) { excl[tid * 8 + i] = e; e += v8[i]; }
    }
    __syncthreads();
    for (int i = tid; i < nodes_n; i += 256)
        offs[obase + node0 + i] = base + excl[i];
    for (int i = tid; i < 512; i += 256) deg[i] = 0;   // reuse as rank ctr
    if (tid == 0 && node0 + 512 >= N_NODES)
        offs[obase + N_NODES] = base + cnt;            // layer sentinel
    __syncthreads();
    for (int i = tid; i < cnt; i += 256) {
        uint v = ent[i];
        int dl = v >> 17;
        int r = atomicAdd(&deg[dl], 1);
        esrc[base + excl[dl] + r] = v;                 // packed src|dl<<17
    }
}

// ---------------------------------------------------------------------------
// Edge weights: w[j] = exp(leaky_relu(a_s[src] + a_d[dst])).
// 4 blocks per bucket; dst recovered from the packed esrc entry + bucket id.
// Moves the random a_s gather + exp off aggregate's critical path.
// ---------------------------------------------------------------------------
__global__ __launch_bounds__(256) void weights_kernel(
    const float* __restrict__ a_s, const float* __restrict__ a_d,
    const uint* __restrict__ esrc, const int* __restrict__ cursor,
    const int* __restrict__ bbase, float* __restrict__ wv, int bucket0)
{
    const int b = bucket0 + (blockIdx.x >> 2);
    const int cnt = min(cursor[b], CAP);
    const int base = bbase[b];
    const int node0 = (b - bucket0) << BSHIFT;
    for (int i = (blockIdx.x & 3) * 256 + threadIdx.x; i < cnt; i += 1024) {
        uint v = esrc[base + i];
        float e = a_s[v & 0x1ffff] + a_d[node0 + (v >> 17)];
        e = (e >= 0.0f) ? e : 0.2f * e;
        wv[base + i] = __expf(e);
    }
}

// ---------------------------------------------------------------------------
// Softmax aggregation, slot-based: 4 nodes per wave, lane = (slot, c16).
// Each lane owns 8 channels of ONE node across its whole edge list:
//  - zero cross-lane shuffles (src/w loads are 16-lane broadcast loads)
//  - dsum accumulated redundantly per lane (no butterfly)
//  - no acc fold, no epilogue reductions
// 2-deep pipeline: esrc/w prefetched 2 ahead, h-row 1 ahead -> no dependent
// load stall inside the loop. MODE 1 skips nodes with vflag==0.
// ---------------------------------------------------------------------------
template <int MODE>
__global__ __launch_bounds__(256) void aggregate(
    const ushort* __restrict__ hb, const float* __restrict__ wv,
    const float* __restrict__ bias,
    const int* __restrict__ offs, const uint* __restrict__ esrc,
    const int* __restrict__ vflag, void* __restrict__ outp, int obase)
{
    const int wave = threadIdx.x >> 6;
    const int lane = threadIdx.x & 63;
    const int slot = lane >> 4;
    const int c16  = lane & 15;
    const int node = (blockIdx.x * 4 + wave) * 4 + slot;  // grid*16 == N_NODES

    int start = offs[obase + node];
    int end   = offs[obase + node + 1];
    bool active = true;
    if (MODE == 1) { active = (vflag[node] != 0); if (!active) end = start; }

    const long coff = (long)(c16 << 3);
    float acc[8] = {0, 0, 0, 0, 0, 0, 0, 0};
    float dsum = 0.0f;

    if (start < end) {
        const int e1 = end - 1;
        uint v1 = 0; float w0, w1; uint4 h0;
        {
            uint v0 = esrc[start];
            w0 = wv[start];
            int jc = min(start + 1, e1);
            v1 = esrc[jc];
            w1 = (start + 1 < end) ? wv[jc] : 0.0f;
            h0 = *reinterpret_cast<const uint4*>(hb + ((long)(v0 & 0x1ffff) << 7) + coff);
        }
        for (int j = start; j < end; ++j) {
            const int j2 = j + 2;
            const int jc = min(j2, e1);
            uint  v2 = esrc[jc];
            float w2 = (j2 < end) ? wv[jc] : 0.0f;
            uint4 h1 = *reinterpret_cast<const uint4*>(hb + ((long)(v1 & 0x1ffff) << 7) + coff);
            dsum += w0;
            acc[0] = fmaf(w0, __uint_as_float(h0.x << 16),         acc[0]);
            acc[1] = fmaf(w0, __uint_as_float(h0.x & 0xffff0000u), acc[1]);
            acc[2] = fmaf(w0, __uint_as_float(h0.y << 16),         acc[2]);
            acc[3] = fmaf(w0, __uint_as_float(h0.y & 0xffff0000u), acc[3]);
            acc[4] = fmaf(w0, __uint_as_float(h0.z << 16),         acc[4]);
            acc[5] = fmaf(w0, __uint_as_float(h0.z & 0xffff0000u), acc[5]);
            acc[6] = fmaf(w0, __uint_as_float(h0.w << 16),         acc[6]);
            acc[7] = fmaf(w0, __uint_as_float(h0.w & 0xffff0000u), acc[7]);
            w0 = w1; h0 = h1; v1 = v2; w1 = w2;
        }
    }

    if (MODE == 1 && !active) return;

    const float inv = 1.0f / (dsum + 1e-16f);
    const int c0 = c16 << 3;
    const float4 b0 = *reinterpret_cast<const float4*>(bias + c0);
    const float4 b1 = *reinterpret_cast<const float4*>(bias + c0 + 4);
    float res[8];
    res[0] = fmaf(acc[0], inv, b0.x);
    res[1] = fmaf(acc[1], inv, b0.y);
    res[2] = fmaf(acc[2], inv, b0.z);
    res[3] = fmaf(acc[3], inv, b0.w);
    res[4] = fmaf(acc[4], inv, b1.x);
    res[5] = fmaf(acc[5], inv, b1.y);
    res[6] = fmaf(acc[6], inv, b1.z);
    res[7] = fmaf(acc[7], inv, b1.w);
    if (MODE == 0) {
        uint4 pk;
        pk.x = (uint)f2bf(res[0]) | ((uint)f2bf(res[1]) << 16);
        pk.y = (uint)f2bf(res[2]) | ((uint)f2bf(res[3]) << 16);
        pk.z = (uint)f2bf(res[4]) | ((uint)f2bf(res[5]) << 16);
        pk.w = (uint)f2bf(res[6]) | ((uint)f2bf(res[7]) << 16);
        *reinterpret_cast<uint4*>((ushort*)outp + ((long)node << 7) + c0) = pk;
    } else {
        float* op = (float*)outp + ((long)node << 7) + c0;
        *reinterpret_cast<float4*>(op)     = make_float4(res[0], res[1], res[2], res[3]);
        *reinterpret_cast<float4*>(op + 4) = make_float4(res[4], res[5], res[6], res[7]);
    }
}

__global__ void gather_out(const float* __restrict__ h, const int* __restrict__ idx,
                           float* __restrict__ out)
{
    int g = blockIdx.x * 256 + threadIdx.x;   // over V_OUT*32 float4s
    int v = g >> 5, c4 = (g & 31) << 2;
    long src = (long)idx[v] * C_DIM + c4;
    *reinterpret_cast<float4*>(out + ((long)v * C_DIM + c4)) =
        *reinterpret_cast<const float4*>(h + src);
}

// ---------------------------------------------------------------------------
extern "C" void kernel_launch(void* const* d_in, const int* in_sizes, int n_in,
                              void* d_out, int out_size, void* d_ws, size_t ws_size,
                              hipStream_t stream)
{
    const float* emb = (const float*)d_in[0];
    const float* W1  = (const float*)d_in[1];
    const float* as1 = (const float*)d_in[2];
    const float* ad1 = (const float*)d_in[3];
    const float* b1  = (const float*)d_in[4];
    const float* W2  = (const float*)d_in[5];
    const float* as2 = (const float*)d_in[6];
    const float* ad2 = (const float*)d_in[7];
    const float* b2  = (const float*)d_in[8];
    const int* edges1 = (const int*)d_in[9];
    const int* edges2 = (const int*)d_in[10];
    const int* idxm   = (const int*)d_in[11];
    float* out = (float*)d_out;

    char* p = (char*)d_ws;
    auto alloc = [&](size_t bytes) {
        char* r = p;
        p += (bytes + 255) & ~(size_t)255;
        return r;
    };
    float*  hB   = (float*)alloc((size_t)N_NODES * C_DIM * 4);   // 51.2 MB
    ushort* hb   = (ushort*)alloc((size_t)N_NODES * C_DIM * 2);  // 25.6 MB
    ushort* a1o  = (ushort*)alloc((size_t)N_NODES * C_DIM * 2);  // 25.6 MB
    uint*   slab = (uint*)alloc((size_t)NBUCK2 * CAP * 4);       // 12.9 MB
    uint*   esrc = (uint*)alloc((size_t)EN2 * 4);                // 7.2 MB (packed)
    float*  wvb  = (float*)alloc((size_t)EN2 * 4);               // 7.2 MB edge weights
    int*    offs = (int*)alloc((size_t)(M2 + 1) * 4);
    ushort* W1b  = (ushort*)alloc((size_t)C_DIM * C_DIM * 2);
    ushort* W2b  = (ushort*)alloc((size_t)C_DIM * C_DIM * 2);
    float*  aS   = (float*)alloc((size_t)N_NODES * 4);
    float*  aD   = (float*)alloc((size_t)N_NODES * 4);
    int*  bbase  = (int*)alloc((size_t)NBUCK2 * 4);
    // cursor + vflag contiguous -> one memset covers both
    int*  cursor = (int*)alloc((size_t)NBUCK2 * 4);
    int*  vflag  = (int*)alloc((size_t)N_NODES * 4);

    // ---- zero cursor+vflag in one memset, weight converts, vflag ---------
    hipMemsetAsync(cursor, 0, (size_t)((char*)vflag - (char*)cursor) + (size_t)N_NODES * 4, stream);
    f2bf_kernel<<<(C_DIM * C_DIM / 4 + 255) / 256, 256, 0, stream>>>(W1, W1b, C_DIM * C_DIM / 4);
    f2bf_kernel<<<(C_DIM * C_DIM / 4 + 255) / 256, 256, 0, stream>>>(W2, W2b, C_DIM * C_DIM / 4);
    vflag_kernel<<<(V_OUT + 255) / 256, 256, 0, stream>>>(idxm, vflag);

    // ---- CSR build (both layers) -----------------------------------------
    partition_kernel<<<NCHUNK, 256, 0, stream>>>(edges1, edges2, cursor, slab);
    bucket_scan<<<1, 64, 0, stream>>>(cursor, bbase);
    local_csr<<<NBUCK2, 256, 0, stream>>>(slab, cursor, bbase, offs, esrc);

    // ---- layer 1 (fp32 emb read fused into gemm) -------------------------
    gemm_mfma<1><<<(N_NODES / 16 + 3) / 4, 256, 0, stream>>>(emb, W1b, as1, ad1, hb, aS, aD);
    weights_kernel<<<NBUCK_L * 4, 256, 0, stream>>>(aS, aD, esrc, cursor, bbase, wvb, 0);
    aggregate<0><<<N_NODES / 16, 256, 0, stream>>>(hb, wvb, b1, offs, esrc, vflag, a1o, 0);

    // ---- layer 2 ---------------------------------------------------------
    gemm_mfma<0><<<(N_NODES / 16 + 3) / 4, 256, 0, stream>>>(a1o, W2b, as2, ad2, hb, aS, aD);
    weights_kernel<<<NBUCK_L * 4, 256, 0, stream>>>(aS, aD, esrc, cursor, bbase, wvb, NBUCK_L);
    aggregate<1><<<N_NODES / 16, 256, 0, stream>>>(hb, wvb, b2, offs, esrc, vflag, hB, N_NODES);

    // ---- final gather ----------------------------------------------------
    gather_out<<<(V_OUT * 32) / 256, 256, 0, stream>>>(hB, idxm, out);
}

// Round 7
// 288.181 us; speedup vs baseline: 1.1073x; 1.1073x over previous
//
#include <hip/hip_runtime.h>

#define N_NODES 100000
#define C_DIM 128
#define E_EDGES 800000
#define V_OUT 50000
#define EN (E_EDGES + N_NODES)      /* 900000  per-layer CSR entries */
#define M2 (2 * N_NODES)
#define EN2 (2 * EN)                /* 1800000 */

#define BSHIFT 9                    /* 512 nodes per coarse bucket */
#define NBUCK_L ((N_NODES + 511) >> 9)   /* 196 per layer */
#define NBUCK2 (2 * NBUCK_L)             /* 392 */
#define CAP 8192                    /* slab capacity; avg fill ~4608 */
#define P1_CHUNK 4096
#define P1_PER_T (P1_CHUNK / 256)   /* 16 */
#define NCHUNK ((EN2 + P1_CHUNK - 1) / P1_CHUNK) /* 440 */

#define XPAD 136                    /* LDS row stride (ushorts): 272B, 2-way banks */

typedef unsigned int uint;
typedef unsigned short ushort;
typedef __attribute__((ext_vector_type(8))) short bf16x8;
typedef __attribute__((ext_vector_type(4))) float f32x4;

static __device__ __forceinline__ ushort f2bf(float f) {
    uint u = __float_as_uint(f);
    u += 0x7fffu + ((u >> 16) & 1);   // round-to-nearest-even
    return (ushort)(u >> 16);
}

// ---------------------------------------------------------------------------
// fp32 -> bf16 bulk convert (weights only)
// ---------------------------------------------------------------------------
__global__ void f2bf_kernel(const float* __restrict__ in, ushort* __restrict__ out, int n4)
{
    int i = blockIdx.x * 256 + threadIdx.x;
    if (i >= n4) return;
    float4 v = reinterpret_cast<const float4*>(in)[i];
    ushort4 r;
    r.x = f2bf(v.x); r.y = f2bf(v.y); r.z = f2bf(v.z); r.w = f2bf(v.w);
    reinterpret_cast<ushort4*>(out)[i] = r;
}

// mark nodes that appear in idx_mapping (races benign: all write 1)
__global__ void vflag_kernel(const int* __restrict__ idx, int* __restrict__ vflag)
{
    int v = blockIdx.x * 256 + threadIdx.x;
    if (v < V_OUT) vflag[idx[v]] = 1;
}

// ---------------------------------------------------------------------------
// MFMA GEMM, LDS-staged: block = 64 nodes (4 waves x 16-node tiles).
// X tile (64x128 bf16) and the whole W (128x128 bf16) are staged into LDS
// with fully-coalesced dwordx4 global loads (deep MLP); fragments then come
// from ds_read_b128 (rows padded to 136 ushorts -> only 2-way bank alias).
// fp32 input (layer 1) converts to bf16 during staging.
// Epilogue: direct stores + fused a_s/a_d score reduction (unchanged).
// ---------------------------------------------------------------------------
template <int IN_F32>
__global__ __launch_bounds__(256) void gemm_mfma(
    const void* __restrict__ xin, const ushort* __restrict__ Wb,
    const float* __restrict__ att_s, const float* __restrict__ att_d,
    ushort* __restrict__ hb, float* __restrict__ a_s, float* __restrict__ a_d)
{
    __shared__ ushort xs[64 * XPAD];    // 17.4 KB
    __shared__ ushort ws[128 * XPAD];   // 34.8 KB
    const int tid = threadIdx.x;
    const int nb = blockIdx.x * 64;

    // ---- stage X: thread t -> row t>>2 (clamped), quarter t&3 ------------
    {
        const int row = tid >> 2, q = tid & 3;
        const long srow = min(nb + row, N_NODES - 1);
        ushort* dst = &xs[row * XPAD + q * 32];
        if (IN_F32) {
            const float* src = (const float*)xin + srow * 128 + q * 32;
            #pragma unroll
            for (int i = 0; i < 4; ++i) {
                float4 u = *reinterpret_cast<const float4*>(src + i * 8);
                float4 v = *reinterpret_cast<const float4*>(src + i * 8 + 4);
                uint4 pk;
                pk.x = (uint)f2bf(u.x) | ((uint)f2bf(u.y) << 16);
                pk.y = (uint)f2bf(u.z) | ((uint)f2bf(u.w) << 16);
                pk.z = (uint)f2bf(v.x) | ((uint)f2bf(v.y) << 16);
                pk.w = (uint)f2bf(v.z) | ((uint)f2bf(v.w) << 16);
                *reinterpret_cast<uint4*>(dst + i * 8) = pk;
            }
        } else {
            const ushort* src = (const ushort*)xin + srow * 128 + q * 32;
            #pragma unroll
            for (int i = 0; i < 4; ++i)
                *reinterpret_cast<uint4*>(dst + i * 8) =
                    *reinterpret_cast<const uint4*>(src + i * 8);
        }
    }
    // ---- stage W: thread t -> row t>>1, half t&1 --------------------------
    {
        const int row = tid >> 1, half = tid & 1;
        const ushort* src = Wb + row * 128 + half * 64;
        ushort* dst = &ws[row * XPAD + half * 64];
        #pragma unroll
        for (int i = 0; i < 8; ++i)
            *reinterpret_cast<uint4*>(dst + i * 8) =
                *reinterpret_cast<const uint4*>(src + i * 8);
    }
    __syncthreads();

    const int lane = tid & 63;
    const int wv   = tid >> 6;
    const int n0   = nb + wv * 16;        // N % 16 == 0: tiles never partial
    if (n0 >= N_NODES) return;
    const int m    = lane & 15;
    const int quad = lane >> 4;

    bf16x8 a[4];
    #pragma unroll
    for (int ki = 0; ki < 4; ++ki)
        a[ki] = *reinterpret_cast<const bf16x8*>(&xs[(wv * 16 + m) * XPAD + quad * 8 + ki * 32]);

    float ps[4] = {0, 0, 0, 0}, pd[4] = {0, 0, 0, 0};

    #pragma unroll
    for (int ct = 0; ct < 8; ++ct) {
        const int c = ct * 16 + m;
        f32x4 acc = {0.f, 0.f, 0.f, 0.f};
        #pragma unroll
        for (int ki = 0; ki < 4; ++ki) {
            bf16x8 b = *reinterpret_cast<const bf16x8*>(&ws[c * XPAD + quad * 8 + ki * 32]);
            acc = __builtin_amdgcn_mfma_f32_16x16x32_bf16(a[ki], b, acc, 0, 0, 0);
        }
        const float asc = att_s[c], adc = att_d[c];
        #pragma unroll
        for (int r = 0; r < 4; ++r) {
            const int node = n0 + quad * 4 + r;
            hb[(long)node * 128 + c] = f2bf(acc[r]);
            ps[r] = fmaf(acc[r], asc, ps[r]);
            pd[r] = fmaf(acc[r], adc, pd[r]);
        }
    }
    #pragma unroll
    for (int r = 0; r < 4; ++r) {
        float s = ps[r], d = pd[r];
        #pragma unroll
        for (int x = 1; x < 16; x <<= 1) { s += __shfl_xor(s, x); d += __shfl_xor(d, x); }
        if (m == 0) {
            const int node = n0 + quad * 4 + r;
            a_s[node] = s; a_d[node] = d;
        }
    }
}

// ---------------------------------------------------------------------------
// CSR build, pass 1: partition edges into 392 coarse buckets of 512 dst.
// ---------------------------------------------------------------------------
__global__ __launch_bounds__(256) void partition_kernel(
    const int* __restrict__ e1, const int* __restrict__ e2,
    int* __restrict__ cursor, uint* __restrict__ slab)
{
    __shared__ int cnt[NBUCK2];
    __shared__ int basearr[NBUCK2];
    const int tid = threadIdx.x;
    for (int i = tid; i < NBUCK2; i += 256) cnt[i] = 0;
    __syncthreads();

    const int e0 = blockIdx.x * P1_CHUNK;
    uint ent[P1_PER_T];
    int  bkt[P1_PER_T];
    #pragma unroll
    for (int i = 0; i < P1_PER_T; ++i) {
        int e = e0 + i * 256 + tid;
        bkt[i] = -1;
        if (e < EN2) {
            int src, dst, lb;
            if (e < EN) {
                if (e < E_EDGES) { src = e1[e]; dst = e1[E_EDGES + e]; }
                else             { src = dst = e - E_EDGES; }
                lb = 0;
            } else {
                int f = e - EN;
                if (f < E_EDGES) { src = e2[f]; dst = e2[E_EDGES + f]; }
                else             { src = dst = f - E_EDGES; }
                lb = NBUCK_L;
            }
            bkt[i] = lb + (dst >> BSHIFT);
            ent[i] = (uint)src | ((uint)(dst & 511) << 17);
            atomicAdd(&cnt[bkt[i]], 1);
        }
    }
    __syncthreads();
    for (int b = tid; b < NBUCK2; b += 256) {
        int c = cnt[b];
        basearr[b] = (c > 0) ? atomicAdd(&cursor[b], c) : 0;
        cnt[b] = 0;                       // reuse as rank counter
    }
    __syncthreads();
    #pragma unroll
    for (int i = 0; i < P1_PER_T; ++i) {
        if (bkt[i] >= 0) {
            int r = basearr[bkt[i]] + atomicAdd(&cnt[bkt[i]], 1);
            if (r < CAP) slab[(long)bkt[i] * CAP + r] = ent[i];
        }
    }
}

// exclusive scan of the 392 bucket counts; single wave
__global__ void bucket_scan(const int* __restrict__ cursor, int* __restrict__ bbase)
{
    const int lane = threadIdx.x;     // 64 threads
    int v[7]; int s = 0;
    #pragma unroll
    for (int i = 0; i < 7; ++i) {
        int idx = lane * 7 + i;
        v[i] = (idx < NBUCK2) ? cursor[idx] : 0;
        s += v[i];
    }
    int incl = s;
    #pragma unroll
    for (int d = 1; d < 64; d <<= 1) {
        int t = __shfl_up(incl, d);
        if (lane >= d) incl += t;
    }
    int excl = incl - s;
    #pragma unroll
    for (int i = 0; i < 7; ++i) {
        int idx = lane * 7 + i;
        if (idx < NBUCK2) bbase[idx] = excl;
        excl += v[i];
    }
}

// ---------------------------------------------------------------------------
// CSR build, pass 2: one workgroup per bucket -> local CSR in LDS.
// esrc entries stay PACKED (src | dst_local<<17) so the weights pass can
// recover dst without a separate edst array.
// ---------------------------------------------------------------------------
__global__ __launch_bounds__(256) void local_csr(
    const uint* __restrict__ slab, const int* __restrict__ cursor,
    const int* __restrict__ bbase, int* __restrict__ offs, uint* __restrict__ esrc)
{
    __shared__ uint ent[CAP];         // 32 KB
    __shared__ int deg[512];
    __shared__ int excl[512];
    const int b = blockIdx.x;
    const int tid = threadIdx.x;
    const int cnt = min(cursor[b], CAP);
    const int base = bbase[b];
    const int layer = (b >= NBUCK_L);
    const int node0 = (b - layer * NBUCK_L) << BSHIFT;
    const int obase = layer * N_NODES;
    const int nodes_n = min(512, N_NODES - node0);

    for (int i = tid; i < 512; i += 256) deg[i] = 0;
    __syncthreads();
    for (int i = tid; i < cnt; i += 256) {
        uint v = slab[(long)b * CAP + i];
        ent[i] = v;
        atomicAdd(&deg[v >> 17], 1);
    }
    __syncthreads();
    if (tid < 64) {                   // wave-0 scan of deg[512], 8 per lane
        int v8[8]; int s = 0;
        #pragma unroll
        for (int i = 0; i < 8; ++i) { v8[i] = deg[tid * 8 + i]; s += v8[i]; }
        int incl = s;
        #pragma unroll
        for (int d = 1; d < 64; d <<= 1) {
            int t = __shfl_up(incl, d);
            if (tid >= d) incl += t;
        }
        int e = incl - s;
        #pragma unroll
        for (int i = 0; i < 8; ++i) { excl[tid * 8 + i] = e; e += v8[i]; }
    }
    __syncthreads();
    for (int i = tid; i < nodes_n; i += 256)
        offs[obase + node0 + i] = base + excl[i];
    for (int i = tid; i < 512; i += 256) deg[i] = 0;   // reuse as rank ctr
    if (tid == 0 && node0 + 512 >= N_NODES)
        offs[obase + N_NODES] = base + cnt;            // layer sentinel
    __syncthreads();
    for (int i = tid; i < cnt; i += 256) {
        uint v = ent[i];
        int dl = v >> 17;
        int r = atomicAdd(&deg[dl], 1);
        esrc[base + excl[dl] + r] = v;                 // packed src|dl<<17
    }
}

// ---------------------------------------------------------------------------
// Edge weights: w[j] = exp(leaky_relu(a_s[src] + a_d[dst])).
// 4 blocks per bucket; dst recovered from the packed esrc entry + bucket id.
// ---------------------------------------------------------------------------
__global__ __launch_bounds__(256) void weights_kernel(
    const float* __restrict__ a_s, const float* __restrict__ a_d,
    const uint* __restrict__ esrc, const int* __restrict__ cursor,
    const int* __restrict__ bbase, float* __restrict__ wv, int bucket0)
{
    const int b = bucket0 + (blockIdx.x >> 2);
    const int cnt = min(cursor[b], CAP);
    const int base = bbase[b];
    const int node0 = (b - bucket0) << BSHIFT;
    for (int i = (blockIdx.x & 3) * 256 + threadIdx.x; i < cnt; i += 1024) {
        uint v = esrc[base + i];
        float e = a_s[v & 0x1ffff] + a_d[node0 + (v >> 17)];
        e = (e >= 0.0f) ? e : 0.2f * e;
        wv[base + i] = __expf(e);
    }
}

// ---------------------------------------------------------------------------
// Softmax aggregation, slot-based: 4 nodes per wave, lane = (slot, c16).
// Each lane owns 8 channels of ONE node; zero cross-lane shuffles; 2-deep
// pipeline on esrc/w and h-rows. MODE 1 skips nodes with vflag==0.
// ---------------------------------------------------------------------------
template <int MODE>
__global__ __launch_bounds__(256) void aggregate(
    const ushort* __restrict__ hb, const float* __restrict__ wv,
    const float* __restrict__ bias,
    const int* __restrict__ offs, const uint* __restrict__ esrc,
    const int* __restrict__ vflag, void* __restrict__ outp, int obase)
{
    const int wave = threadIdx.x >> 6;
    const int lane = threadIdx.x & 63;
    const int slot = lane >> 4;
    const int c16  = lane & 15;
    const int node = (blockIdx.x * 4 + wave) * 4 + slot;  // grid*16 == N_NODES

    int start = offs[obase + node];
    int end   = offs[obase + node + 1];
    bool active = true;
    if (MODE == 1) { active = (vflag[node] != 0); if (!active) end = start; }

    const long coff = (long)(c16 << 3);
    float acc[8] = {0, 0, 0, 0, 0, 0, 0, 0};
    float dsum = 0.0f;

    if (start < end) {
        const int e1 = end - 1;
        uint v1 = 0; float w0, w1; uint4 h0;
        {
            uint v0 = esrc[start];
            w0 = wv[start];
            int jc = min(start + 1, e1);
            v1 = esrc[jc];
            w1 = (start + 1 < end) ? wv[jc] : 0.0f;
            h0 = *reinterpret_cast<const uint4*>(hb + ((long)(v0 & 0x1ffff) << 7) + coff);
        }
        for (int j = start; j < end; ++j) {
            const int j2 = j + 2;
            const int jc = min(j2, e1);
            uint  v2 = esrc[jc];
            float w2 = (j2 < end) ? wv[jc] : 0.0f;
            uint4 h1 = *reinterpret_cast<const uint4*>(hb + ((long)(v1 & 0x1ffff) << 7) + coff);
            dsum += w0;
            acc[0] = fmaf(w0, __uint_as_float(h0.x << 16),         acc[0]);
            acc[1] = fmaf(w0, __uint_as_float(h0.x & 0xffff0000u), acc[1]);
            acc[2] = fmaf(w0, __uint_as_float(h0.y << 16),         acc[2]);
            acc[3] = fmaf(w0, __uint_as_float(h0.y & 0xffff0000u), acc[3]);
            acc[4] = fmaf(w0, __uint_as_float(h0.z << 16),         acc[4]);
            acc[5] = fmaf(w0, __uint_as_float(h0.z & 0xffff0000u), acc[5]);
            acc[6] = fmaf(w0, __uint_as_float(h0.w << 16),         acc[6]);
            acc[7] = fmaf(w0, __uint_as_float(h0.w & 0xffff0000u), acc[7]);
            w0 = w1; h0 = h1; v1 = v2; w1 = w2;
        }
    }

    if (MODE == 1 && !active) return;

    const float inv = 1.0f / (dsum + 1e-16f);
    const int c0 = c16 << 3;
    const float4 b0 = *reinterpret_cast<const float4*>(bias + c0);
    const float4 b1 = *reinterpret_cast<const float4*>(bias + c0 + 4);
    float res[8];
    res[0] = fmaf(acc[0], inv, b0.x);
    res[1] = fmaf(acc[1], inv, b0.y);
    res[2] = fmaf(acc[2], inv, b0.z);
    res[3] = fmaf(acc[3], inv, b0.w);
    res[4] = fmaf(acc[4], inv, b1.x);
    res[5] = fmaf(acc[5], inv, b1.y);
    res[6] = fmaf(acc[6], inv, b1.z);
    res[7] = fmaf(acc[7], inv, b1.w);
    if (MODE == 0) {
        uint4 pk;
        pk.x = (uint)f2bf(res[0]) | ((uint)f2bf(res[1]) << 16);
        pk.y = (uint)f2bf(res[2]) | ((uint)f2bf(res[3]) << 16);
        pk.z = (uint)f2bf(res[4]) | ((uint)f2bf(res[5]) << 16);
        pk.w = (uint)f2bf(res[6]) | ((uint)f2bf(res[7]) << 16);
        *reinterpret_cast<uint4*>((ushort*)outp + ((long)node << 7) + c0) = pk;
    } else {
        float* op = (float*)outp + ((long)node << 7) + c0;
        *reinterpret_cast<float4*>(op)     = make_float4(res[0], res[1], res[2], res[3]);
        *reinterpret_cast<float4*>(op + 4) = make_float4(res[4], res[5], res[6], res[7]);
    }
}

__global__ void gather_out(const float* __restrict__ h, const int* __restrict__ idx,
                           float* __restrict__ out)
{
    int g = blockIdx.x * 256 + threadIdx.x;   // over V_OUT*32 float4s
    int v = g >> 5, c4 = (g & 31) << 2;
    long src = (long)idx[v] * C_DIM + c4;
    *reinterpret_cast<float4*>(out + ((long)v * C_DIM + c4)) =
        *reinterpret_cast<const float4*>(h + src);
}

// ---------------------------------------------------------------------------
extern "C" void kernel_launch(void* const* d_in, const int* in_sizes, int n_in,
                              void* d_out, int out_size, void* d_ws, size_t ws_size,
                              hipStream_t stream)
{
    const float* emb = (const float*)d_in[0];
    const float* W1  = (const float*)d_in[1];
    const float* as1 = (const float*)d_in[2];
    const float* ad1 = (const float*)d_in[3];
    const float* b1  = (const float*)d_in[4];
    const float* W2  = (const float*)d_in[5];
    const float* as2 = (const float*)d_in[6];
    const float* ad2 = (const float*)d_in[7];
    const float* b2  = (const float*)d_in[8];
    const int* edges1 = (const int*)d_in[9];
    const int* edges2 = (const int*)d_in[10];
    const int* idxm   = (const int*)d_in[11];
    float* out = (float*)d_out;

    char* p = (char*)d_ws;
    auto alloc = [&](size_t bytes) {
        char* r = p;
        p += (bytes + 255) & ~(size_t)255;
        return r;
    };
    float*  hB   = (float*)alloc((size_t)N_NODES * C_DIM * 4);   // 51.2 MB
    ushort* hb   = (ushort*)alloc((size_t)N_NODES * C_DIM * 2);  // 25.6 MB
    ushort* a1o  = (ushort*)alloc((size_t)N_NODES * C_DIM * 2);  // 25.6 MB
    uint*   slab = (uint*)alloc((size_t)NBUCK2 * CAP * 4);       // 12.9 MB
    uint*   esrc = (uint*)alloc((size_t)EN2 * 4);                // 7.2 MB (packed)
    float*  wvb  = (float*)alloc((size_t)EN2 * 4);               // 7.2 MB edge weights
    int*    offs = (int*)alloc((size_t)(M2 + 1) * 4);
    ushort* W1b  = (ushort*)alloc((size_t)C_DIM * C_DIM * 2);
    ushort* W2b  = (ushort*)alloc((size_t)C_DIM * C_DIM * 2);
    float*  aS   = (float*)alloc((size_t)N_NODES * 4);
    float*  aD   = (float*)alloc((size_t)N_NODES * 4);
    int*  bbase  = (int*)alloc((size_t)NBUCK2 * 4);
    // cursor + vflag contiguous -> one memset covers both
    int*  cursor = (int*)alloc((size_t)NBUCK2 * 4);
    int*  vflag  = (int*)alloc((size_t)N_NODES * 4);

    // ---- zero cursor+vflag in one memset, weight converts, vflag ---------
    hipMemsetAsync(cursor, 0, (size_t)((char*)vflag - (char*)cursor) + (size_t)N_NODES * 4, stream);
    f2bf_kernel<<<(C_DIM * C_DIM / 4 + 255) / 256, 256, 0, stream>>>(W1, W1b, C_DIM * C_DIM / 4);
    f2bf_kernel<<<(C_DIM * C_DIM / 4 + 255) / 256, 256, 0, stream>>>(W2, W2b, C_DIM * C_DIM / 4);
    vflag_kernel<<<(V_OUT + 255) / 256, 256, 0, stream>>>(idxm, vflag);

    // ---- CSR build (both layers) -----------------------------------------
    partition_kernel<<<NCHUNK, 256, 0, stream>>>(edges1, edges2, cursor, slab);
    bucket_scan<<<1, 64, 0, stream>>>(cursor, bbase);
    local_csr<<<NBUCK2, 256, 0, stream>>>(slab, cursor, bbase, offs, esrc);

    // ---- layer 1 (fp32 emb read fused into gemm staging) -----------------
    gemm_mfma<1><<<(N_NODES + 63) / 64, 256, 0, stream>>>(emb, W1b, as1, ad1, hb, aS, aD);
    weights_kernel<<<NBUCK_L * 4, 256, 0, stream>>>(aS, aD, esrc, cursor, bbase, wvb, 0);
    aggregate<0><<<N_NODES / 16, 256, 0, stream>>>(hb, wvb, b1, offs, esrc, vflag, a1o, 0);

    // ---- layer 2 ---------------------------------------------------------
    gemm_mfma<0><<<(N_NODES + 63) / 64, 256, 0, stream>>>(a1o, W2b, as2, ad2, hb, aS, aD);
    weights_kernel<<<NBUCK_L * 4, 256, 0, stream>>>(aS, aD, esrc, cursor, bbase, wvb, NBUCK_L);
    aggregate<1><<<N_NODES / 16, 256, 0, stream>>>(hb, wvb, b2, offs, esrc, vflag, hB, N_NODES);

    // ---- final gather ----------------------------------------------------
    gather_out<<<(V_OUT * 32) / 256, 256, 0, stream>>>(hB, idxm, out);
}

// Round 8
// 284.090 us; speedup vs baseline: 1.1233x; 1.0144x over previous
//
#include <hip/hip_runtime.h>

#define N_NODES 100000
#define C_DIM 128
#define E_EDGES 800000
#define V_OUT 50000
#define EN (E_EDGES + N_NODES)      /* 900000  per-layer CSR entries */
#define M2 (2 * N_NODES)
#define EN2 (2 * EN)                /* 1800000 */

#define BSHIFT 9                    /* 512 nodes per coarse bucket */
#define NBUCK_L ((N_NODES + 511) >> 9)   /* 196 per layer */
#define NBUCK2 (2 * NBUCK_L)             /* 392 */
#define CAP 8192                    /* slab capacity; avg fill ~4608 */
#define P1_CHUNK 4096
#define P1_PER_T (P1_CHUNK / 256)   /* 16 */
#define NCHUNK ((EN2 + P1_CHUNK - 1) / P1_CHUNK) /* 440 */

#define XPAD 136                    /* LDS row stride (ushorts): 272B, 2-way banks */

typedef unsigned int uint;
typedef unsigned short ushort;
typedef __attribute__((ext_vector_type(8))) short bf16x8;
typedef __attribute__((ext_vector_type(4))) float f32x4;

static __device__ __forceinline__ ushort f2bf(float f) {
    uint u = __float_as_uint(f);
    u += 0x7fffu + ((u >> 16) & 1);   // round-to-nearest-even
    return (ushort)(u >> 16);
}

// ---------------------------------------------------------------------------
// prep: convert W1,W2 to bf16 + scatter vflag, one fused kernel.
// blocks 0..15 -> W1, 16..31 -> W2, 32.. -> vflag (196 blocks).
// ---------------------------------------------------------------------------
#define PREP_WBLK (C_DIM * C_DIM / 4 / 256)   /* 16 */
#define PREP_VBLK ((V_OUT + 255) / 256)       /* 196 */
__global__ void prep_kernel(const float* __restrict__ W1, const float* __restrict__ W2,
                            ushort* __restrict__ W1b, ushort* __restrict__ W2b,
                            const int* __restrict__ idx, int* __restrict__ vflag)
{
    const int b = blockIdx.x;
    if (b < 2 * PREP_WBLK) {
        const float* in  = (b < PREP_WBLK) ? W1 : W2;
        ushort* outp     = (b < PREP_WBLK) ? W1b : W2b;
        int i = (b % PREP_WBLK) * 256 + threadIdx.x;
        float4 v = reinterpret_cast<const float4*>(in)[i];
        ushort4 r;
        r.x = f2bf(v.x); r.y = f2bf(v.y); r.z = f2bf(v.z); r.w = f2bf(v.w);
        reinterpret_cast<ushort4*>(outp)[i] = r;
    } else {
        int v = (b - 2 * PREP_WBLK) * 256 + threadIdx.x;
        if (v < V_OUT) vflag[idx[v]] = 1;    // races benign: all write 1
    }
}

// ---------------------------------------------------------------------------
// MFMA GEMM, LDS-staged: block = 64 nodes (4 waves x 16-node tiles).
// X tile (64x128 bf16) and the whole W (128x128 bf16) staged via coalesced
// dwordx4 loads; fragments from ds_read_b128 (rows padded to 136 ushorts ->
// 2-way bank alias only, free). fp32 input converts during staging.
// ---------------------------------------------------------------------------
template <int IN_F32>
__global__ __launch_bounds__(256) void gemm_mfma(
    const void* __restrict__ xin, const ushort* __restrict__ Wb,
    const float* __restrict__ att_s, const float* __restrict__ att_d,
    ushort* __restrict__ hb, float* __restrict__ a_s, float* __restrict__ a_d)
{
    __shared__ ushort xs[64 * XPAD];    // 17.4 KB
    __shared__ ushort ws[128 * XPAD];   // 34.8 KB
    const int tid = threadIdx.x;
    const int nb = blockIdx.x * 64;

    // ---- stage X: thread t -> row t>>2 (clamped), quarter t&3 ------------
    {
        const int row = tid >> 2, q = tid & 3;
        const long srow = min(nb + row, N_NODES - 1);
        ushort* dst = &xs[row * XPAD + q * 32];
        if (IN_F32) {
            const float* src = (const float*)xin + srow * 128 + q * 32;
            #pragma unroll
            for (int i = 0; i < 4; ++i) {
                float4 u = *reinterpret_cast<const float4*>(src + i * 8);
                float4 v = *reinterpret_cast<const float4*>(src + i * 8 + 4);
                uint4 pk;
                pk.x = (uint)f2bf(u.x) | ((uint)f2bf(u.y) << 16);
                pk.y = (uint)f2bf(u.z) | ((uint)f2bf(u.w) << 16);
                pk.z = (uint)f2bf(v.x) | ((uint)f2bf(v.y) << 16);
                pk.w = (uint)f2bf(v.z) | ((uint)f2bf(v.w) << 16);
                *reinterpret_cast<uint4*>(dst + i * 8) = pk;
            }
        } else {
            const ushort* src = (const ushort*)xin + srow * 128 + q * 32;
            #pragma unroll
            for (int i = 0; i < 4; ++i)
                *reinterpret_cast<uint4*>(dst + i * 8) =
                    *reinterpret_cast<const uint4*>(src + i * 8);
        }
    }
    // ---- stage W: thread t -> row t>>1, half t&1 --------------------------
    {
        const int row = tid >> 1, half = tid & 1;
        const ushort* src = Wb + row * 128 + half * 64;
        ushort* dst = &ws[row * XPAD + half * 64];
        #pragma unroll
        for (int i = 0; i < 8; ++i)
            *reinterpret_cast<uint4*>(dst + i * 8) =
                *reinterpret_cast<const uint4*>(src + i * 8);
    }
    __syncthreads();

    const int lane = tid & 63;
    const int wv   = tid >> 6;
    const int n0   = nb + wv * 16;        // N % 16 == 0: tiles never partial
    if (n0 >= N_NODES) return;
    const int m    = lane & 15;
    const int quad = lane >> 4;

    bf16x8 a[4];
    #pragma unroll
    for (int ki = 0; ki < 4; ++ki)
        a[ki] = *reinterpret_cast<const bf16x8*>(&xs[(wv * 16 + m) * XPAD + quad * 8 + ki * 32]);

    float ps[4] = {0, 0, 0, 0}, pd[4] = {0, 0, 0, 0};

    #pragma unroll
    for (int ct = 0; ct < 8; ++ct) {
        const int c = ct * 16 + m;
        f32x4 acc = {0.f, 0.f, 0.f, 0.f};
        #pragma unroll
        for (int ki = 0; ki < 4; ++ki) {
            bf16x8 b = *reinterpret_cast<const bf16x8*>(&ws[c * XPAD + quad * 8 + ki * 32]);
            acc = __builtin_amdgcn_mfma_f32_16x16x32_bf16(a[ki], b, acc, 0, 0, 0);
        }
        const float asc = att_s[c], adc = att_d[c];
        #pragma unroll
        for (int r = 0; r < 4; ++r) {
            const int node = n0 + quad * 4 + r;
            hb[(long)node * 128 + c] = f2bf(acc[r]);
            ps[r] = fmaf(acc[r], asc, ps[r]);
            pd[r] = fmaf(acc[r], adc, pd[r]);
        }
    }
    #pragma unroll
    for (int r = 0; r < 4; ++r) {
        float s = ps[r], d = pd[r];
        #pragma unroll
        for (int x = 1; x < 16; x <<= 1) { s += __shfl_xor(s, x); d += __shfl_xor(d, x); }
        if (m == 0) {
            const int node = n0 + quad * 4 + r;
            a_s[node] = s; a_d[node] = d;
        }
    }
}

// ---------------------------------------------------------------------------
// CSR build, pass 1: partition edges into 392 coarse buckets of 512 dst.
// ---------------------------------------------------------------------------
__global__ __launch_bounds__(256) void partition_kernel(
    const int* __restrict__ e1, const int* __restrict__ e2,
    int* __restrict__ cursor, uint* __restrict__ slab)
{
    __shared__ int cnt[NBUCK2];
    __shared__ int basearr[NBUCK2];
    const int tid = threadIdx.x;
    for (int i = tid; i < NBUCK2; i += 256) cnt[i] = 0;
    __syncthreads();

    const int e0 = blockIdx.x * P1_CHUNK;
    uint ent[P1_PER_T];
    int  bkt[P1_PER_T];
    #pragma unroll
    for (int i = 0; i < P1_PER_T; ++i) {
        int e = e0 + i * 256 + tid;
        bkt[i] = -1;
        if (e < EN2) {
            int src, dst, lb;
            if (e < EN) {
                if (e < E_EDGES) { src = e1[e]; dst = e1[E_EDGES + e]; }
                else             { src = dst = e - E_EDGES; }
                lb = 0;
            } else {
                int f = e - EN;
                if (f < E_EDGES) { src = e2[f]; dst = e2[E_EDGES + f]; }
                else             { src = dst = f - E_EDGES; }
                lb = NBUCK_L;
            }
            bkt[i] = lb + (dst >> BSHIFT);
            ent[i] = (uint)src | ((uint)(dst & 511) << 17);
            atomicAdd(&cnt[bkt[i]], 1);
        }
    }
    __syncthreads();
    for (int b = tid; b < NBUCK2; b += 256) {
        int c = cnt[b];
        basearr[b] = (c > 0) ? atomicAdd(&cursor[b], c) : 0;
        cnt[b] = 0;                       // reuse as rank counter
    }
    __syncthreads();
    #pragma unroll
    for (int i = 0; i < P1_PER_T; ++i) {
        if (bkt[i] >= 0) {
            int r = basearr[bkt[i]] + atomicAdd(&cnt[bkt[i]], 1);
            if (r < CAP) slab[(long)bkt[i] * CAP + r] = ent[i];
        }
    }
}

// exclusive scan of the 392 bucket counts; single wave
__global__ void bucket_scan(const int* __restrict__ cursor, int* __restrict__ bbase)
{
    const int lane = threadIdx.x;     // 64 threads
    int v[7]; int s = 0;
    #pragma unroll
    for (int i = 0; i < 7; ++i) {
        int idx = lane * 7 + i;
        v[i] = (idx < NBUCK2) ? cursor[idx] : 0;
        s += v[i];
    }
    int incl = s;
    #pragma unroll
    for (int d = 1; d < 64; d <<= 1) {
        int t = __shfl_up(incl, d);
        if (lane >= d) incl += t;
    }
    int excl = incl - s;
    #pragma unroll
    for (int i = 0; i < 7; ++i) {
        int idx = lane * 7 + i;
        if (idx < NBUCK2) bbase[idx] = excl;
        excl += v[i];
    }
}

// ---------------------------------------------------------------------------
// CSR build, pass 2: one workgroup per bucket -> local CSR in LDS.
// esrc entries stay PACKED (src | dst_local<<17).
// ---------------------------------------------------------------------------
__global__ __launch_bounds__(256) void local_csr(
    const uint* __restrict__ slab, const int* __restrict__ cursor,
    const int* __restrict__ bbase, int* __restrict__ offs, uint* __restrict__ esrc)
{
    __shared__ uint ent[CAP];         // 32 KB
    __shared__ int deg[512];
    __shared__ int excl[512];
    const int b = blockIdx.x;
    const int tid = threadIdx.x;
    const int cnt = min(cursor[b], CAP);
    const int base = bbase[b];
    const int layer = (b >= NBUCK_L);
    const int node0 = (b - layer * NBUCK_L) << BSHIFT;
    const int obase = layer * N_NODES;
    const int nodes_n = min(512, N_NODES - node0);

    for (int i = tid; i < 512; i += 256) deg[i] = 0;
    __syncthreads();
    for (int i = tid; i < cnt; i += 256) {
        uint v = slab[(long)b * CAP + i];
        ent[i] = v;
        atomicAdd(&deg[v >> 17], 1);
    }
    __syncthreads();
    if (tid < 64) {                   // wave-0 scan of deg[512], 8 per lane
        int v8[8]; int s = 0;
        #pragma unroll
        for (int i = 0; i < 8; ++i) { v8[i] = deg[tid * 8 + i]; s += v8[i]; }
        int incl = s;
        #pragma unroll
        for (int d = 1; d < 64; d <<= 1) {
            int t = __shfl_up(incl, d);
            if (tid >= d) incl += t;
        }
        int e = incl - s;
        #pragma unroll
        for (int i = 0; i < 8; ++i) { excl[tid * 8 + i] = e; e += v8[i]; }
    }
    __syncthreads();
    for (int i = tid; i < nodes_n; i += 256)
        offs[obase + node0 + i] = base + excl[i];
    for (int i = tid; i < 512; i += 256) deg[i] = 0;   // reuse as rank ctr
    if (tid == 0 && node0 + 512 >= N_NODES)
        offs[obase + N_NODES] = base + cnt;            // layer sentinel
    __syncthreads();
    for (int i = tid; i < cnt; i += 256) {
        uint v = ent[i];
        int dl = v >> 17;
        int r = atomicAdd(&deg[dl], 1);
        esrc[base + excl[dl] + r] = v;                 // packed src|dl<<17
    }
}

// ---------------------------------------------------------------------------
// Softmax aggregation, slot-based with INLINE weights: 4 nodes/wave,
// lane = (slot, c16); lane owns 8 channels of one node, zero shuffles.
// 3-stage pipeline: esrc 3-ahead -> a_s[src] 2-ahead (400KB, L2-resident,
// same-address across the 16 slot lanes -> broadcast fetch) -> exp 1-ahead;
// h-rows 2-deep (h0/h1/h2 rotate). MODE 1 skips nodes with vflag==0.
// ---------------------------------------------------------------------------
template <int MODE>
__global__ __launch_bounds__(256) void aggregate(
    const ushort* __restrict__ hb, const float* __restrict__ a_s,
    const float* __restrict__ a_d, const float* __restrict__ bias,
    const int* __restrict__ offs, const uint* __restrict__ esrc,
    const int* __restrict__ vflag, void* __restrict__ outp, int obase)
{
    const int wave = threadIdx.x >> 6;
    const int lane = threadIdx.x & 63;
    const int slot = lane >> 4;
    const int c16  = lane & 15;
    const int node = (blockIdx.x * 4 + wave) * 4 + slot;  // grid*16 == N_NODES

    int start = offs[obase + node];
    int end   = offs[obase + node + 1];
    bool active = true;
    if (MODE == 1) { active = (vflag[node] != 0); if (!active) end = start; }

    const long coff = (long)(c16 << 3);
    float acc[8] = {0, 0, 0, 0, 0, 0, 0, 0};
    float dsum = 0.0f;

    if (start < end) {
        const float ad = a_d[node];
        const int e1 = end - 1;
        // prologue: fill the pipeline
        uint v0 = esrc[start];
        uint v1 = esrc[min(start + 1, e1)];
        uint v2 = esrc[min(start + 2, e1)];
        float as1 = a_s[v1 & 0x1ffff];
        uint4 h0 = *reinterpret_cast<const uint4*>(hb + ((long)(v0 & 0x1ffff) << 7) + coff);
        uint4 h1 = *reinterpret_cast<const uint4*>(hb + ((long)(v1 & 0x1ffff) << 7) + coff);
        float w0;
        {
            float e = a_s[v0 & 0x1ffff] + ad;
            e = (e >= 0.0f) ? e : 0.2f * e;
            w0 = __expf(e);
        }
        for (int j = start; j < end; ++j) {
            uint  v3  = esrc[min(j + 3, e1)];
            float as2 = a_s[v2 & 0x1ffff];
            uint4 h2  = *reinterpret_cast<const uint4*>(hb + ((long)(v2 & 0x1ffff) << 7) + coff);
            float e   = as1 + ad;
            e = (e >= 0.0f) ? e : 0.2f * e;
            float w1 = __expf(e);

            dsum += w0;
            acc[0] = fmaf(w0, __uint_as_float(h0.x << 16),         acc[0]);
            acc[1] = fmaf(w0, __uint_as_float(h0.x & 0xffff0000u), acc[1]);
            acc[2] = fmaf(w0, __uint_as_float(h0.y << 16),         acc[2]);
            acc[3] = fmaf(w0, __uint_as_float(h0.y & 0xffff0000u), acc[3]);
            acc[4] = fmaf(w0, __uint_as_float(h0.z << 16),         acc[4]);
            acc[5] = fmaf(w0, __uint_as_float(h0.z & 0xffff0000u), acc[5]);
            acc[6] = fmaf(w0, __uint_as_float(h0.w << 16),         acc[6]);
            acc[7] = fmaf(w0, __uint_as_float(h0.w & 0xffff0000u), acc[7]);
            // rotate pipeline
            w0 = w1; h0 = h1; h1 = h2; as1 = as2; v2 = v3;
        }
    }

    if (MODE == 1 && !active) return;

    const float inv = 1.0f / (dsum + 1e-16f);
    const int c0 = c16 << 3;
    const float4 b0 = *reinterpret_cast<const float4*>(bias + c0);
    const float4 b1 = *reinterpret_cast<const float4*>(bias + c0 + 4);
    float res[8];
    res[0] = fmaf(acc[0], inv, b0.x);
    res[1] = fmaf(acc[1], inv, b0.y);
    res[2] = fmaf(acc[2], inv, b0.z);
    res[3] = fmaf(acc[3], inv, b0.w);
    res[4] = fmaf(acc[4], inv, b1.x);
    res[5] = fmaf(acc[5], inv, b1.y);
    res[6] = fmaf(acc[6], inv, b1.z);
    res[7] = fmaf(acc[7], inv, b1.w);
    if (MODE == 0) {
        uint4 pk;
        pk.x = (uint)f2bf(res[0]) | ((uint)f2bf(res[1]) << 16);
        pk.y = (uint)f2bf(res[2]) | ((uint)f2bf(res[3]) << 16);
        pk.z = (uint)f2bf(res[4]) | ((uint)f2bf(res[5]) << 16);
        pk.w = (uint)f2bf(res[6]) | ((uint)f2bf(res[7]) << 16);
        *reinterpret_cast<uint4*>((ushort*)outp + ((long)node << 7) + c0) = pk;
    } else {
        float* op = (float*)outp + ((long)node << 7) + c0;
        *reinterpret_cast<float4*>(op)     = make_float4(res[0], res[1], res[2], res[3]);
        *reinterpret_cast<float4*>(op + 4) = make_float4(res[4], res[5], res[6], res[7]);
    }
}

__global__ void gather_out(const float* __restrict__ h, const int* __restrict__ idx,
                           float* __restrict__ out)
{
    int g = blockIdx.x * 256 + threadIdx.x;   // over V_OUT*32 float4s
    int v = g >> 5, c4 = (g & 31) << 2;
    long src = (long)idx[v] * C_DIM + c4;
    *reinterpret_cast<float4*>(out + ((long)v * C_DIM + c4)) =
        *reinterpret_cast<const float4*>(h + src);
}

// ---------------------------------------------------------------------------
extern "C" void kernel_launch(void* const* d_in, const int* in_sizes, int n_in,
                              void* d_out, int out_size, void* d_ws, size_t ws_size,
                              hipStream_t stream)
{
    const float* emb = (const float*)d_in[0];
    const float* W1  = (const float*)d_in[1];
    const float* as1 = (const float*)d_in[2];
    const float* ad1 = (const float*)d_in[3];
    const float* b1  = (const float*)d_in[4];
    const float* W2  = (const float*)d_in[5];
    const float* as2 = (const float*)d_in[6];
    const float* ad2 = (const float*)d_in[7];
    const float* b2  = (const float*)d_in[8];
    const int* edges1 = (const int*)d_in[9];
    const int* edges2 = (const int*)d_in[10];
    const int* idxm   = (const int*)d_in[11];
    float* out = (float*)d_out;

    char* p = (char*)d_ws;
    auto alloc = [&](size_t bytes) {
        char* r = p;
        p += (bytes + 255) & ~(size_t)255;
        return r;
    };
    float*  hB   = (float*)alloc((size_t)N_NODES * C_DIM * 4);   // 51.2 MB
    ushort* hb   = (ushort*)alloc((size_t)N_NODES * C_DIM * 2);  // 25.6 MB
    ushort* a1o  = (ushort*)alloc((size_t)N_NODES * C_DIM * 2);  // 25.6 MB
    uint*   slab = (uint*)alloc((size_t)NBUCK2 * CAP * 4);       // 12.9 MB
    uint*   esrc = (uint*)alloc((size_t)EN2 * 4);                // 7.2 MB (packed)
    int*    offs = (int*)alloc((size_t)(M2 + 1) * 4);
    ushort* W1b  = (ushort*)alloc((size_t)C_DIM * C_DIM * 2);
    ushort* W2b  = (ushort*)alloc((size_t)C_DIM * C_DIM * 2);
    float*  aS   = (float*)alloc((size_t)N_NODES * 4);
    float*  aD   = (float*)alloc((size_t)N_NODES * 4);
    int*  bbase  = (int*)alloc((size_t)NBUCK2 * 4);
    // cursor + vflag contiguous -> one memset covers both
    int*  cursor = (int*)alloc((size_t)NBUCK2 * 4);
    int*  vflag  = (int*)alloc((size_t)N_NODES * 4);

    // ---- zero cursor+vflag in one memset; fused prep (W converts + vflag)
    hipMemsetAsync(cursor, 0, (size_t)((char*)vflag - (char*)cursor) + (size_t)N_NODES * 4, stream);
    prep_kernel<<<2 * PREP_WBLK + PREP_VBLK, 256, 0, stream>>>(W1, W2, W1b, W2b, idxm, vflag);

    // ---- CSR build (both layers) -----------------------------------------
    partition_kernel<<<NCHUNK, 256, 0, stream>>>(edges1, edges2, cursor, slab);
    bucket_scan<<<1, 64, 0, stream>>>(cursor, bbase);
    local_csr<<<NBUCK2, 256, 0, stream>>>(slab, cursor, bbase, offs, esrc);

    // ---- layer 1 (fp32 emb read fused into gemm staging) -----------------
    gemm_mfma<1><<<(N_NODES + 63) / 64, 256, 0, stream>>>(emb, W1b, as1, ad1, hb, aS, aD);
    aggregate<0><<<N_NODES / 16, 256, 0, stream>>>(hb, aS, aD, b1, offs, esrc, vflag, a1o, 0);

    // ---- layer 2 ---------------------------------------------------------
    gemm_mfma<0><<<(N_NODES + 63) / 64, 256, 0, stream>>>(a1o, W2b, as2, ad2, hb, aS, aD);
    aggregate<1><<<N_NODES / 16, 256, 0, stream>>>(hb, aS, aD, b2, offs, esrc, vflag, hB, N_NODES);

    // ---- final gather ----------------------------------------------------
    gather_out<<<(V_OUT * 32) / 256, 256, 0, stream>>>(hB, idxm, out);
}

// Round 9
// 269.772 us; speedup vs baseline: 1.1829x; 1.0531x over previous
//
#include <hip/hip_runtime.h>

#define N_NODES 100000
#define C_DIM 128
#define E_EDGES 800000
#define V_OUT 50000
#define EN (E_EDGES + N_NODES)      /* 900000  per-layer CSR entries */
#define M2 (2 * N_NODES)
#define EN2 (2 * EN)                /* 1800000 */

#define BSHIFT 9                    /* 512 nodes per coarse bucket */
#define NBUCK_L ((N_NODES + 511) >> 9)   /* 196 per layer */
#define NBUCK2 (2 * NBUCK_L)             /* 392 */
#define CAP 8192                    /* slab capacity; avg fill ~4608 */
#define P1_CHUNK 4096
#define P1_PER_T (P1_CHUNK / 256)   /* 16 */
#define NCHUNK ((EN2 + P1_CHUNK - 1) / P1_CHUNK) /* 440 */

#define XPAD 136                    /* LDS row stride (ushorts): 272B, 2-way banks */
#define LDS_E 768                   /* staged edges per 16-node block; mean 144, +15 sigma safe */

typedef unsigned int uint;
typedef unsigned short ushort;
typedef __attribute__((ext_vector_type(8))) short bf16x8;
typedef __attribute__((ext_vector_type(4))) float f32x4;

static __device__ __forceinline__ ushort f2bf(float f) {
    uint u = __float_as_uint(f);
    u += 0x7fffu + ((u >> 16) & 1);   // round-to-nearest-even
    return (ushort)(u >> 16);
}

// ---------------------------------------------------------------------------
// prep: convert W1,W2 to bf16 + scatter vflag, one fused kernel.
// ---------------------------------------------------------------------------
#define PREP_WBLK (C_DIM * C_DIM / 4 / 256)   /* 16 */
#define PREP_VBLK ((V_OUT + 255) / 256)       /* 196 */
__global__ void prep_kernel(const float* __restrict__ W1, const float* __restrict__ W2,
                            ushort* __restrict__ W1b, ushort* __restrict__ W2b,
                            const int* __restrict__ idx, int* __restrict__ vflag)
{
    const int b = blockIdx.x;
    if (b < 2 * PREP_WBLK) {
        const float* in  = (b < PREP_WBLK) ? W1 : W2;
        ushort* outp     = (b < PREP_WBLK) ? W1b : W2b;
        int i = (b % PREP_WBLK) * 256 + threadIdx.x;
        float4 v = reinterpret_cast<const float4*>(in)[i];
        ushort4 r;
        r.x = f2bf(v.x); r.y = f2bf(v.y); r.z = f2bf(v.z); r.w = f2bf(v.w);
        reinterpret_cast<ushort4*>(outp)[i] = r;
    } else {
        int v = (b - 2 * PREP_WBLK) * 256 + threadIdx.x;
        if (v < V_OUT) vflag[idx[v]] = 1;    // races benign: all write 1
    }
}

// ---------------------------------------------------------------------------
// MFMA GEMM, LDS-staged: block = 64 nodes (4 waves x 16-node tiles).
// ---------------------------------------------------------------------------
template <int IN_F32>
__global__ __launch_bounds__(256) void gemm_mfma(
    const void* __restrict__ xin, const ushort* __restrict__ Wb,
    const float* __restrict__ att_s, const float* __restrict__ att_d,
    ushort* __restrict__ hb, float* __restrict__ a_s, float* __restrict__ a_d)
{
    __shared__ ushort xs[64 * XPAD];    // 17.4 KB
    __shared__ ushort ws[128 * XPAD];   // 34.8 KB
    const int tid = threadIdx.x;
    const int nb = blockIdx.x * 64;

    // ---- stage X: thread t -> row t>>2 (clamped), quarter t&3 ------------
    {
        const int row = tid >> 2, q = tid & 3;
        const long srow = min(nb + row, N_NODES - 1);
        ushort* dst = &xs[row * XPAD + q * 32];
        if (IN_F32) {
            const float* src = (const float*)xin + srow * 128 + q * 32;
            #pragma unroll
            for (int i = 0; i < 4; ++i) {
                float4 u = *reinterpret_cast<const float4*>(src + i * 8);
                float4 v = *reinterpret_cast<const float4*>(src + i * 8 + 4);
                uint4 pk;
                pk.x = (uint)f2bf(u.x) | ((uint)f2bf(u.y) << 16);
                pk.y = (uint)f2bf(u.z) | ((uint)f2bf(u.w) << 16);
                pk.z = (uint)f2bf(v.x) | ((uint)f2bf(v.y) << 16);
                pk.w = (uint)f2bf(v.z) | ((uint)f2bf(v.w) << 16);
                *reinterpret_cast<uint4*>(dst + i * 8) = pk;
            }
        } else {
            const ushort* src = (const ushort*)xin + srow * 128 + q * 32;
            #pragma unroll
            for (int i = 0; i < 4; ++i)
                *reinterpret_cast<uint4*>(dst + i * 8) =
                    *reinterpret_cast<const uint4*>(src + i * 8);
        }
    }
    // ---- stage W: thread t -> row t>>1, half t&1 --------------------------
    {
        const int row = tid >> 1, half = tid & 1;
        const ushort* src = Wb + row * 128 + half * 64;
        ushort* dst = &ws[row * XPAD + half * 64];
        #pragma unroll
        for (int i = 0; i < 8; ++i)
            *reinterpret_cast<uint4*>(dst + i * 8) =
                *reinterpret_cast<const uint4*>(src + i * 8);
    }
    __syncthreads();

    const int lane = tid & 63;
    const int wv   = tid >> 6;
    const int n0   = nb + wv * 16;        // N % 16 == 0: tiles never partial
    if (n0 >= N_NODES) return;
    const int m    = lane & 15;
    const int quad = lane >> 4;

    bf16x8 a[4];
    #pragma unroll
    for (int ki = 0; ki < 4; ++ki)
        a[ki] = *reinterpret_cast<const bf16x8*>(&xs[(wv * 16 + m) * XPAD + quad * 8 + ki * 32]);

    float ps[4] = {0, 0, 0, 0}, pd[4] = {0, 0, 0, 0};

    #pragma unroll
    for (int ct = 0; ct < 8; ++ct) {
        const int c = ct * 16 + m;
        f32x4 acc = {0.f, 0.f, 0.f, 0.f};
        #pragma unroll
        for (int ki = 0; ki < 4; ++ki) {
            bf16x8 b = *reinterpret_cast<const bf16x8*>(&ws[c * XPAD + quad * 8 + ki * 32]);
            acc = __builtin_amdgcn_mfma_f32_16x16x32_bf16(a[ki], b, acc, 0, 0, 0);
        }
        const float asc = att_s[c], adc = att_d[c];
        #pragma unroll
        for (int r = 0; r < 4; ++r) {
            const int node = n0 + quad * 4 + r;
            hb[(long)node * 128 + c] = f2bf(acc[r]);
            ps[r] = fmaf(acc[r], asc, ps[r]);
            pd[r] = fmaf(acc[r], adc, pd[r]);
        }
    }
    #pragma unroll
    for (int r = 0; r < 4; ++r) {
        float s = ps[r], d = pd[r];
        #pragma unroll
        for (int x = 1; x < 16; x <<= 1) { s += __shfl_xor(s, x); d += __shfl_xor(d, x); }
        if (m == 0) {
            const int node = n0 + quad * 4 + r;
            a_s[node] = s; a_d[node] = d;
        }
    }
}

// ---------------------------------------------------------------------------
// CSR build, pass 1: partition edges into 392 coarse buckets of 512 dst.
// ---------------------------------------------------------------------------
__global__ __launch_bounds__(256) void partition_kernel(
    const int* __restrict__ e1, const int* __restrict__ e2,
    int* __restrict__ cursor, uint* __restrict__ slab)
{
    __shared__ int cnt[NBUCK2];
    __shared__ int basearr[NBUCK2];
    const int tid = threadIdx.x;
    for (int i = tid; i < NBUCK2; i += 256) cnt[i] = 0;
    __syncthreads();

    const int e0 = blockIdx.x * P1_CHUNK;
    uint ent[P1_PER_T];
    int  bkt[P1_PER_T];
    #pragma unroll
    for (int i = 0; i < P1_PER_T; ++i) {
        int e = e0 + i * 256 + tid;
        bkt[i] = -1;
        if (e < EN2) {
            int src, dst, lb;
            if (e < EN) {
                if (e < E_EDGES) { src = e1[e]; dst = e1[E_EDGES + e]; }
                else             { src = dst = e - E_EDGES; }
                lb = 0;
            } else {
                int f = e - EN;
                if (f < E_EDGES) { src = e2[f]; dst = e2[E_EDGES + f]; }
                else             { src = dst = f - E_EDGES; }
                lb = NBUCK_L;
            }
            bkt[i] = lb + (dst >> BSHIFT);
            ent[i] = (uint)src | ((uint)(dst & 511) << 17);
            atomicAdd(&cnt[bkt[i]], 1);
        }
    }
    __syncthreads();
    for (int b = tid; b < NBUCK2; b += 256) {
        int c = cnt[b];
        basearr[b] = (c > 0) ? atomicAdd(&cursor[b], c) : 0;
        cnt[b] = 0;                       // reuse as rank counter
    }
    __syncthreads();
    #pragma unroll
    for (int i = 0; i < P1_PER_T; ++i) {
        if (bkt[i] >= 0) {
            int r = basearr[bkt[i]] + atomicAdd(&cnt[bkt[i]], 1);
            if (r < CAP) slab[(long)bkt[i] * CAP + r] = ent[i];
        }
    }
}

// exclusive scan of the 392 bucket counts; single wave
__global__ void bucket_scan(const int* __restrict__ cursor, int* __restrict__ bbase)
{
    const int lane = threadIdx.x;     // 64 threads
    int v[7]; int s = 0;
    #pragma unroll
    for (int i = 0; i < 7; ++i) {
        int idx = lane * 7 + i;
        v[i] = (idx < NBUCK2) ? cursor[idx] : 0;
        s += v[i];
    }
    int incl = s;
    #pragma unroll
    for (int d = 1; d < 64; d <<= 1) {
        int t = __shfl_up(incl, d);
        if (lane >= d) incl += t;
    }
    int excl = incl - s;
    #pragma unroll
    for (int i = 0; i < 7; ++i) {
        int idx = lane * 7 + i;
        if (idx < NBUCK2) bbase[idx] = excl;
        excl += v[i];
    }
}

// ---------------------------------------------------------------------------
// CSR build, pass 2: one workgroup per bucket -> local CSR in LDS.
// esrc entries stay PACKED (src | dst_local<<17).
// ---------------------------------------------------------------------------
__global__ __launch_bounds__(256) void local_csr(
    const uint* __restrict__ slab, const int* __restrict__ cursor,
    const int* __restrict__ bbase, int* __restrict__ offs, uint* __restrict__ esrc)
{
    __shared__ uint ent[CAP];         // 32 KB
    __shared__ int deg[512];
    __shared__ int excl[512];
    const int b = blockIdx.x;
    const int tid = threadIdx.x;
    const int cnt = min(cursor[b], CAP);
    const int base = bbase[b];
    const int layer = (b >= NBUCK_L);
    const int node0 = (b - layer * NBUCK_L) << BSHIFT;
    const int obase = layer * N_NODES;
    const int nodes_n = min(512, N_NODES - node0);

    for (int i = tid; i < 512; i += 256) deg[i] = 0;
    __syncthreads();
    for (int i = tid; i < cnt; i += 256) {
        uint v = slab[(long)b * CAP + i];
        ent[i] = v;
        atomicAdd(&deg[v >> 17], 1);
    }
    __syncthreads();
    if (tid < 64) {                   // wave-0 scan of deg[512], 8 per lane
        int v8[8]; int s = 0;
        #pragma unroll
        for (int i = 0; i < 8; ++i) { v8[i] = deg[tid * 8 + i]; s += v8[i]; }
        int incl = s;
        #pragma unroll
        for (int d = 1; d < 64; d <<= 1) {
            int t = __shfl_up(incl, d);
            if (tid >= d) incl += t;
        }
        int e = incl - s;
        #pragma unroll
        for (int i = 0; i < 8; ++i) { excl[tid * 8 + i] = e; e += v8[i]; }
    }
    __syncthreads();
    for (int i = tid; i < nodes_n; i += 256)
        offs[obase + node0 + i] = base + excl[i];
    for (int i = tid; i < 512; i += 256) deg[i] = 0;   // reuse as rank ctr
    if (tid == 0 && node0 + 512 >= N_NODES)
        offs[obase + N_NODES] = base + cnt;            // layer sentinel
    __syncthreads();
    for (int i = tid; i < cnt; i += 256) {
        uint v = ent[i];
        int dl = v >> 17;
        int r = atomicAdd(&deg[dl], 1);
        esrc[base + excl[dl] + r] = v;                 // packed src|dl<<17
    }
}

// ---------------------------------------------------------------------------
// Softmax aggregation, TWO-PHASE: block = 16 nodes whose esrc range is one
// contiguous span (16 | 512, blocks never straddle buckets).
// Phase 1 (edge-parallel): compute w = exp(leaky(a_s[src]+a_d[dst])) for the
//   block's ~145 edges; stash {packed_v, w} as uint2 in LDS. Coalesced esrc
//   read; a_s gather latencies overlap across independent edge lanes.
// Phase 2 (slot loop): 4 nodes/wave, lane=(slot,c16); per edge one
//   ds_read_b64 (16-lane broadcast, conflict-free) + the h-row gather,
//   h prefetched 2-deep. No global esrc/a_s/exp on the critical path.
// Overflow (block edges > LDS_E, prob ~0): slow correct path from global.
// MODE 1 skips nodes with vflag==0.
// ---------------------------------------------------------------------------
template <int MODE>
__global__ __launch_bounds__(256) void aggregate(
    const ushort* __restrict__ hb, const float* __restrict__ a_s,
    const float* __restrict__ a_d, const float* __restrict__ bias,
    const int* __restrict__ offs, const uint* __restrict__ esrc,
    const int* __restrict__ vflag, void* __restrict__ outp, int obase)
{
    __shared__ uint2 ew[LDS_E];       // 6 KB
    const int tid = threadIdx.x;
    const int node0 = blockIdx.x * 16;            // grid = N/16 = 6250
    const int bnode0 = (node0 >> BSHIFT) << BSHIFT;  // bucket's first node (layer-local)
    const int bstart = offs[obase + node0];
    const int bend   = offs[obase + node0 + 16];
    const int nE = bend - bstart;

    // ---- phase 1: stage {v, w} for the block's edges ---------------------
    for (int i = tid; i < min(nE, LDS_E); i += 256) {
        uint v = esrc[bstart + i];
        float e = a_s[v & 0x1ffff] + a_d[bnode0 + (v >> 17)];
        e = (e >= 0.0f) ? e : 0.2f * e;
        ew[i] = make_uint2(v, __float_as_uint(__expf(e)));
    }
    __syncthreads();

    // ---- phase 2: slot loop ----------------------------------------------
    const int wave = tid >> 6;
    const int lane = tid & 63;
    const int slot = lane >> 4;
    const int c16  = lane & 15;
    const int node = node0 + wave * 4 + slot;
    if (MODE == 1 && vflag[node] == 0) return;    // uniform across the slot's 16 lanes

    const int start = offs[obase + node];
    const int end   = offs[obase + node + 1];
    const long coff = (long)(c16 << 3);
    float acc[8] = {0, 0, 0, 0, 0, 0, 0, 0};
    float dsum = 0.0f;

    if (start < end) {
        if (nE <= LDS_E) {
            // fast path: per-edge state from LDS
            const int jr = start - bstart, jend = end - bstart;
            const int e1 = jend - 1;
            uint2 p0 = ew[jr];
            uint2 p1 = ew[min(jr + 1, e1)];
            uint2 p2 = ew[min(jr + 2, e1)];
            uint4 h0 = *reinterpret_cast<const uint4*>(hb + ((long)(p0.x & 0x1ffff) << 7) + coff);
            uint4 h1 = *reinterpret_cast<const uint4*>(hb + ((long)(p1.x & 0x1ffff) << 7) + coff);
            float w1 = __uint_as_float(p1.y);
            float w0 = __uint_as_float(p0.y);
            for (int j = jr; j < jend; ++j) {
                uint2 p3 = ew[min(j + 3, e1)];
                uint4 h2 = *reinterpret_cast<const uint4*>(hb + ((long)(p2.x & 0x1ffff) << 7) + coff);
                float w2 = __uint_as_float(p2.y);
                dsum += w0;
                acc[0] = fmaf(w0, __uint_as_float(h0.x << 16),         acc[0]);
                acc[1] = fmaf(w0, __uint_as_float(h0.x & 0xffff0000u), acc[1]);
                acc[2] = fmaf(w0, __uint_as_float(h0.y << 16),         acc[2]);
                acc[3] = fmaf(w0, __uint_as_float(h0.y & 0xffff0000u), acc[3]);
                acc[4] = fmaf(w0, __uint_as_float(h0.z << 16),         acc[4]);
                acc[5] = fmaf(w0, __uint_as_float(h0.z & 0xffff0000u), acc[5]);
                acc[6] = fmaf(w0, __uint_as_float(h0.w << 16),         acc[6]);
                acc[7] = fmaf(w0, __uint_as_float(h0.w & 0xffff0000u), acc[7]);
                w0 = w1; w1 = w2; h0 = h1; h1 = h2; p2 = p3;
            }
        } else {
            // slow correct path (never taken in practice)
            const float ad = a_d[node];
            for (int j = start; j < end; ++j) {
                uint v = esrc[j];
                float e = a_s[v & 0x1ffff] + ad;
                e = (e >= 0.0f) ? e : 0.2f * e;
                float w = __expf(e);
                uint4 h = *reinterpret_cast<const uint4*>(hb + ((long)(v & 0x1ffff) << 7) + coff);
                dsum += w;
                acc[0] = fmaf(w, __uint_as_float(h.x << 16),         acc[0]);
                acc[1] = fmaf(w, __uint_as_float(h.x & 0xffff0000u), acc[1]);
                acc[2] = fmaf(w, __uint_as_float(h.y << 16),         acc[2]);
                acc[3] = fmaf(w, __uint_as_float(h.y & 0xffff0000u), acc[3]);
                acc[4] = fmaf(w, __uint_as_float(h.z << 16),         acc[4]);
                acc[5] = fmaf(w, __uint_as_float(h.z & 0xffff0000u), acc[5]);
                acc[6] = fmaf(w, __uint_as_float(h.w << 16),         acc[6]);
                acc[7] = fmaf(w, __uint_as_float(h.w & 0xffff0000u), acc[7]);
            }
        }
    }

    const float inv = 1.0f / (dsum + 1e-16f);
    const int c0 = c16 << 3;
    const float4 b0 = *reinterpret_cast<const float4*>(bias + c0);
    const float4 b1 = *reinterpret_cast<const float4*>(bias + c0 + 4);
    float res[8];
    res[0] = fmaf(acc[0], inv, b0.x);
    res[1] = fmaf(acc[1], inv, b0.y);
    res[2] = fmaf(acc[2], inv, b0.z);
    res[3] = fmaf(acc[3], inv, b0.w);
    res[4] = fmaf(acc[4], inv, b1.x);
    res[5] = fmaf(acc[5], inv, b1.y);
    res[6] = fmaf(acc[6], inv, b1.z);
    res[7] = fmaf(acc[7], inv, b1.w);
    if (MODE == 0) {
        uint4 pk;
        pk.x = (uint)f2bf(res[0]) | ((uint)f2bf(res[1]) << 16);
        pk.y = (uint)f2bf(res[2]) | ((uint)f2bf(res[3]) << 16);
        pk.z = (uint)f2bf(res[4]) | ((uint)f2bf(res[5]) << 16);
        pk.w = (uint)f2bf(res[6]) | ((uint)f2bf(res[7]) << 16);
        *reinterpret_cast<uint4*>((ushort*)outp + ((long)node << 7) + c0) = pk;
    } else {
        float* op = (float*)outp + ((long)node << 7) + c0;
        *reinterpret_cast<float4*>(op)     = make_float4(res[0], res[1], res[2], res[3]);
        *reinterpret_cast<float4*>(op + 4) = make_float4(res[4], res[5], res[6], res[7]);
    }
}

__global__ void gather_out(const float* __restrict__ h, const int* __restrict__ idx,
                           float* __restrict__ out)
{
    int g = blockIdx.x * 256 + threadIdx.x;   // over V_OUT*32 float4s
    int v = g >> 5, c4 = (g & 31) << 2;
    long src = (long)idx[v] * C_DIM + c4;
    *reinterpret_cast<float4*>(out + ((long)v * C_DIM + c4)) =
        *reinterpret_cast<const float4*>(h + src);
}

// ---------------------------------------------------------------------------
extern "C" void kernel_launch(void* const* d_in, const int* in_sizes, int n_in,
                              void* d_out, int out_size, void* d_ws, size_t ws_size,
                              hipStream_t stream)
{
    const float* emb = (const float*)d_in[0];
    const float* W1  = (const float*)d_in[1];
    const float* as1 = (const float*)d_in[2];
    const float* ad1 = (const float*)d_in[3];
    const float* b1  = (const float*)d_in[4];
    const float* W2  = (const float*)d_in[5];
    const float* as2 = (const float*)d_in[6];
    const float* ad2 = (const float*)d_in[7];
    const float* b2  = (const float*)d_in[8];
    const int* edges1 = (const int*)d_in[9];
    const int* edges2 = (const int*)d_in[10];
    const int* idxm   = (const int*)d_in[11];
    float* out = (float*)d_out;

    char* p = (char*)d_ws;
    auto alloc = [&](size_t bytes) {
        char* r = p;
        p += (bytes + 255) & ~(size_t)255;
        return r;
    };
    float*  hB   = (float*)alloc((size_t)N_NODES * C_DIM * 4);   // 51.2 MB
    ushort* hb   = (ushort*)alloc((size_t)N_NODES * C_DIM * 2);  // 25.6 MB
    ushort* a1o  = (ushort*)alloc((size_t)N_NODES * C_DIM * 2);  // 25.6 MB
    uint*   slab = (uint*)alloc((size_t)NBUCK2 * CAP * 4);       // 12.9 MB
    uint*   esrc = (uint*)alloc((size_t)EN2 * 4);                // 7.2 MB (packed)
    int*    offs = (int*)alloc((size_t)(M2 + 1) * 4);
    ushort* W1b  = (ushort*)alloc((size_t)C_DIM * C_DIM * 2);
    ushort* W2b  = (ushort*)alloc((size_t)C_DIM * C_DIM * 2);
    float*  aS   = (float*)alloc((size_t)N_NODES * 4);
    float*  aD   = (float*)alloc((size_t)N_NODES * 4);
    int*  bbase  = (int*)alloc((size_t)NBUCK2 * 4);
    // cursor + vflag contiguous -> one memset covers both
    int*  cursor = (int*)alloc((size_t)NBUCK2 * 4);
    int*  vflag  = (int*)alloc((size_t)N_NODES * 4);

    // ---- zero cursor+vflag in one memset; fused prep (W converts + vflag)
    hipMemsetAsync(cursor, 0, (size_t)((char*)vflag - (char*)cursor) + (size_t)N_NODES * 4, stream);
    prep_kernel<<<2 * PREP_WBLK + PREP_VBLK, 256, 0, stream>>>(W1, W2, W1b, W2b, idxm, vflag);

    // ---- CSR build (both layers) -----------------------------------------
    partition_kernel<<<NCHUNK, 256, 0, stream>>>(edges1, edges2, cursor, slab);
    bucket_scan<<<1, 64, 0, stream>>>(cursor, bbase);
    local_csr<<<NBUCK2, 256, 0, stream>>>(slab, cursor, bbase, offs, esrc);

    // ---- layer 1 (fp32 emb read fused into gemm staging) -----------------
    gemm_mfma<1><<<(N_NODES + 63) / 64, 256, 0, stream>>>(emb, W1b, as1, ad1, hb, aS, aD);
    aggregate<0><<<N_NODES / 16, 256, 0, stream>>>(hb, aS, aD, b1, offs, esrc, vflag, a1o, 0);

    // ---- layer 2 ---------------------------------------------------------
    gemm_mfma<0><<<(N_NODES + 63) / 64, 256, 0, stream>>>(a1o, W2b, as2, ad2, hb, aS, aD);
    aggregate<1><<<N_NODES / 16, 256, 0, stream>>>(hb, aS, aD, b2, offs, esrc, vflag, hB, N_NODES);

    // ---- final gather ----------------------------------------------------
    gather_out<<<(V_OUT * 32) / 256, 256, 0, stream>>>(hB, idxm, out);
}